// Round 5
// baseline (402.930 us; speedup 1.0000x reference)
//
#include <hip/hip_runtime.h>

#define B_  2
#define V_  4
#define VS_ 3   // source views
#define C_  32
#define G_  8
#define D_  32
#define H_  128
#define W_  160

// ---------------------------------------------------------------------------
// 4x4 inverse (Gauss-Jordan with partial pivoting)
// ---------------------------------------------------------------------------
__device__ void inv4x4(const float* m, float* out) {
    float a[4][8];
    for (int i = 0; i < 4; i++) {
        for (int j = 0; j < 4; j++) {
            a[i][j]     = m[i * 4 + j];
            a[i][j + 4] = (i == j) ? 1.f : 0.f;
        }
    }
    for (int c = 0; c < 4; c++) {
        int piv = c;
        float best = fabsf(a[c][c]);
        for (int r = c + 1; r < 4; r++) {
            float v = fabsf(a[r][c]);
            if (v > best) { best = v; piv = r; }
        }
        if (piv != c) {
            for (int j = 0; j < 8; j++) {
                float t = a[c][j]; a[c][j] = a[piv][j]; a[piv][j] = t;
            }
        }
        float pv = 1.f / a[c][c];
        for (int j = 0; j < 8; j++) a[c][j] *= pv;
        for (int r = 0; r < 4; r++) {
            if (r == c) continue;
            float f = a[r][c];
            for (int j = 0; j < 8; j++) a[r][j] -= f * a[c][j];
        }
    }
    for (int i = 0; i < 4; i++)
        for (int j = 0; j < 4; j++) out[i * 4 + j] = a[i][j + 4];
}

__device__ void make_proj(const float* p, float* o) {
    const float* ext = p;
    const float* K   = p + 16;
    for (int i = 0; i < 16; i++) o[i] = ext[i];
    for (int i = 0; i < 3; i++) {
        for (int j = 0; j < 4; j++) {
            float s = 0.f;
            for (int k = 0; k < 3; k++) s += K[i * 4 + k] * ext[k * 4 + j];
            o[i * 4 + j] = s;
        }
    }
}

// Per (b, src view): store rot(9) + trans(3) of src_proj @ inv(ref_proj)
__global__ void setup_proj_kernel(const float* __restrict__ proj,
                                  float* __restrict__ projp) {
    int t = threadIdx.x;
    if (t >= B_ * VS_) return;
    int b = t / VS_;
    int v = t % VS_ + 1;

    float refm[16], srcm[16], invr[16], P[16];
    make_proj(proj + ((size_t)(b * V_ + 0) * 2) * 16, refm);
    make_proj(proj + ((size_t)(b * V_ + v) * 2) * 16, srcm);
    inv4x4(refm, invr);
    for (int i = 0; i < 4; i++) {
        for (int j = 0; j < 4; j++) {
            float s = 0.f;
            for (int k = 0; k < 4; k++) s += srcm[i * 4 + k] * invr[k * 4 + j];
            P[i * 4 + j] = s;
        }
    }
    float* o = projp + t * 12;
    o[0] = P[0];  o[1] = P[1];  o[2]  = P[2];
    o[3] = P[4];  o[4] = P[5];  o[5]  = P[6];
    o[6] = P[8];  o[7] = P[9];  o[8]  = P[10];
    o[9] = P[3];  o[10] = P[7]; o[11] = P[11];
}

// ---------------------------------------------------------------------------
// (N, C, H, W) -> (N, H, W, C) channels-last transpose, one block per (n, y) row
// ---------------------------------------------------------------------------
__global__ __launch_bounds__(256) void transpose_kernel(const float* __restrict__ in,
                                                        float* __restrict__ out) {
    __shared__ float tile[C_][W_ + 1];
    int n = blockIdx.x / H_;
    int y = blockIdx.x % H_;
    for (int idx = threadIdx.x; idx < C_ * W_; idx += 256) {
        int c = idx / W_;
        int x = idx - c * W_;
        tile[c][x] = in[(((size_t)n * C_ + c) * H_ + y) * W_ + x];
    }
    __syncthreads();
    float* op = out + ((size_t)n * H_ + y) * W_ * C_;
    for (int idx = threadIdx.x; idx < W_ * C_; idx += 256) {
        int c = idx & (C_ - 1);
        int x = idx >> 5;
        op[idx] = tile[c][x];
    }
}

// ---------------------------------------------------------------------------
// Fused warp + group-correlation + view softmax + final softmax/argmax.
// One thread per (b, h, w, d); block = 8 pixels x 32 depths.
// Per-view offsets computed in-loop; live state ~45 VGPR so we can force the
// 64-VGPR occupancy bin (8 waves/SIMD) without spilling.
// ---------------------------------------------------------------------------
__global__ __launch_bounds__(256, 8) void fused_kernel(const float* __restrict__ ref_fea,
                                                       const float* __restrict__ srcT,
                                                       const float* __restrict__ projp,
                                                       const float* __restrict__ depth_hypo,
                                                       const float* __restrict__ reg_w,
                                                       float* __restrict__ out) {
    const int WT = W_ / 8;
    int bid = blockIdx.x;
    int b   = bid / (H_ * WT);
    int rem = bid % (H_ * WT);
    int h   = rem / WT;
    int w0  = (rem % WT) * 8;

    int tid = threadIdx.x;
    int d   = tid & 31;
    int p   = tid >> 5;
    int w   = w0 + p;

    // stage ref vectors (and reg_w-weighted copy) + depth planes into LDS.
    // [8][36]: rows stay 16B-aligned for b128 reads; store banks (4*px+c)%32
    // are conflict-free.
    __shared__ float s_ref[8][36];
    __shared__ float s_rw[8][36];
    __shared__ float s_depth[8][33];
    {
        int c  = tid >> 3;
        int px = tid & 7;
        float val = ref_fea[(((size_t)b * C_ + c) * H_ + h) * W_ + w0 + px];
        s_ref[px][c] = val;
        s_rw[px][c]  = val * reg_w[c >> 2];
        // coalesced depth stage: 8 threads read 32B contiguous per depth row
        s_depth[px][c] = depth_hypo[(((size_t)b * D_ + c) * H_ + h) * W_ + w0 + px];
    }
    __syncthreads();

    float depth = s_depth[p][d];

    float xf = (float)w, yf = (float)h;

    float Sv[VS_], Rv[VS_];
#pragma unroll
    for (int v = 0; v < VS_; ++v) {
        // ---- tap offsets + weights (branchless), computed per view ----
        const float* M = projp + (b * VS_ + v) * 12;
        float rx = M[0] * xf + M[1] * yf + M[2];
        float ry = M[3] * xf + M[4] * yf + M[5];
        float rz = M[6] * xf + M[7] * yf + M[8];
        float X = rx * depth + M[9];
        float Y = ry * depth + M[10];
        float Z = rz * depth + M[11];
        if (Z == 0.f) Z = 1e-9f;
        float ix = X / Z;
        float iy = Y / Z;
        float x0f = floorf(ix), y0f = floorf(iy);
        float wx1 = ix - x0f, wy1 = iy - y0f;
        float wx0 = 1.f - wx1, wy0 = 1.f - wy1;

        int x0 = (int)x0f, y0 = (int)y0f;
        int xc0 = min(max(x0, 0), W_ - 1);
        int xc1 = min(max(x0 + 1, 0), W_ - 1);
        int yc0 = min(max(y0, 0), H_ - 1);
        int yc1 = min(max(y0 + 1, 0), H_ - 1);

        float vx0 = (x0f >= 0.f  && x0f <= (float)(W_ - 1)) ? 1.f : 0.f;
        float vx1 = (x0f >= -1.f && x0f <= (float)(W_ - 2)) ? 1.f : 0.f;
        float vy0 = (y0f >= 0.f  && y0f <= (float)(H_ - 1)) ? 1.f : 0.f;
        float vy1 = (y0f >= -1.f && y0f <= (float)(H_ - 2)) ? 1.f : 0.f;

        float ax0 = wx0 * vx0, ax1 = wx1 * vx1;
        float ay0 = wy0 * vy0, ay1 = wy1 * vy1;
        float w00 = ax0 * ay0, w10 = ax1 * ay0;
        float w01 = ax0 * ay1, w11 = ax1 * ay1;

        int r0 = yc0 * W_, r1 = yc1 * W_;
        int o00 = (r0 + xc0) * (C_ / 4);
        int o10 = (r0 + xc1) * (C_ / 4);
        int o01 = (r1 + xc0) * (C_ / 4);
        int o11 = (r1 + xc1) * (C_ / 4);

        const float4* sp = (const float4*)(srcT + (size_t)(v * B_ + b) * H_ * W_ * C_);
        float sS = 0.f, sR = 0.f;
#pragma unroll
        for (int g = 0; g < G_; ++g) {
            float4 t00 = sp[o00 + g];
            float4 t10 = sp[o10 + g];
            float4 t01 = sp[o01 + g];
            float4 t11 = sp[o11 + g];
            float wsx = w00 * t00.x + w10 * t10.x + w01 * t01.x + w11 * t11.x;
            float wsy = w00 * t00.y + w10 * t10.y + w01 * t01.y + w11 * t11.y;
            float wsz = w00 * t00.z + w10 * t10.z + w01 * t01.z + w11 * t11.z;
            float wsw = w00 * t00.w + w10 * t10.w + w01 * t01.w + w11 * t11.w;
            float4 r  = *(const float4*)&s_ref[p][g * 4];
            float4 r2 = *(const float4*)&s_rw[p][g * 4];
            sS += r.x  * wsx + r.y  * wsy + r.z  * wsz + r.w  * wsw;
            sR += r2.x * wsx + r2.y * wsy + r2.z * wsz + r2.w * wsw;
        }
        Sv[v] = sS;
        Rv[v] = sR;
    }

    // ---- per-view softmax over D + scalar accumulation ----
    float cwsum = 1e-8f;
    float acc   = 0.f;
#pragma unroll
    for (int v = 0; v < VS_; ++v) {
        float t = Sv[v] * 0.125f;  // *0.25 (group mean) * 0.5 (1/ATTN_TEMP)

        float m = t;
#pragma unroll
        for (int mask = 16; mask >= 1; mask >>= 1)
            m = fmaxf(m, __shfl_xor(m, mask));
        float e = __expf(t - m);
        float s = e;
#pragma unroll
        for (int mask = 16; mask >= 1; mask >>= 1)
            s += __shfl_xor(s, mask);
        float cw = e / s * 0.17677669529663689f;  // * 1/sqrt(C)

        cwsum += cw;
        acc   += cw * (Rv[v] * 0.25f);
    }

    float logit = acc / cwsum;

    // final softmax over D
    float m = logit;
#pragma unroll
    for (int mask = 16; mask >= 1; mask >>= 1)
        m = fmaxf(m, __shfl_xor(m, mask));
    float e = __expf(logit - m);
    float s = e;
#pragma unroll
    for (int mask = 16; mask >= 1; mask >>= 1)
        s += __shfl_xor(s, mask);
    float attn = e / s;

    // argmax over D (first max wins, matching jnp.argmax)
    float bv = logit;
    int   bi = d;
#pragma unroll
    for (int mask = 16; mask >= 1; mask >>= 1) {
        float ov = __shfl_xor(bv, mask);
        int   oi = __shfl_xor(bi, mask);
        if (ov > bv || (ov == bv && oi < bi)) { bv = ov; bi = oi; }
    }

    if (d == 0) {
        out[((size_t)b * H_ + h) * W_ + w] = s_depth[p][bi];  // LDS read, no shfl
    }

    // attn store via LDS transpose for 32B-segment coalescing
    __shared__ float s_attn[8][33];
    s_attn[p][d] = attn;
    __syncthreads();
    int po = tid & 7;
    int d2 = tid >> 3;
    float* attn_out = out + (size_t)B_ * H_ * W_;
    attn_out[(((size_t)b * D_ + d2) * H_ + h) * W_ + w0 + po] = s_attn[po][d2];
}

// ---------------------------------------------------------------------------
extern "C" void kernel_launch(void* const* d_in, const int* in_sizes, int n_in,
                              void* d_out, int out_size, void* d_ws, size_t ws_size,
                              hipStream_t stream) {
    const float* ref_fea    = (const float*)d_in[0];
    const float* src_feas   = (const float*)d_in[1];
    const float* proj       = (const float*)d_in[2];
    const float* depth_hypo = (const float*)d_in[3];
    const float* reg_w      = (const float*)d_in[4];
    float* out = (float*)d_out;

    float* projp = (float*)d_ws;                       // 72 floats used
    float* srcT  = projp + 256;                        // VS*B*H*W*C

    setup_proj_kernel<<<1, 64, 0, stream>>>(proj, projp);
    transpose_kernel<<<VS_ * B_ * H_, 256, 0, stream>>>(src_feas, srcT);
    fused_kernel<<<B_ * H_ * (W_ / 8), 256, 0, stream>>>(ref_fea, srcT, projp,
                                                         depth_hypo, reg_w, out);
}

// Round 7
// 207.346 us; speedup vs baseline: 1.9433x; 1.9433x over previous
//
#include <hip/hip_runtime.h>

#define B_  2
#define V_  4
#define VS_ 3   // source views
#define C_  32
#define G_  8
#define D_  32
#define H_  128
#define W_  160
#define CELLS_MAX 96

// ---------------------------------------------------------------------------
// 4x4 inverse (Gauss-Jordan with partial pivoting)
// ---------------------------------------------------------------------------
__device__ void inv4x4(const float* m, float* out) {
    float a[4][8];
    for (int i = 0; i < 4; i++) {
        for (int j = 0; j < 4; j++) {
            a[i][j]     = m[i * 4 + j];
            a[i][j + 4] = (i == j) ? 1.f : 0.f;
        }
    }
    for (int c = 0; c < 4; c++) {
        int piv = c;
        float best = fabsf(a[c][c]);
        for (int r = c + 1; r < 4; r++) {
            float v = fabsf(a[r][c]);
            if (v > best) { best = v; piv = r; }
        }
        if (piv != c) {
            for (int j = 0; j < 8; j++) {
                float t = a[c][j]; a[c][j] = a[piv][j]; a[piv][j] = t;
            }
        }
        float pv = 1.f / a[c][c];
        for (int j = 0; j < 8; j++) a[c][j] *= pv;
        for (int r = 0; r < 4; r++) {
            if (r == c) continue;
            float f = a[r][c];
            for (int j = 0; j < 8; j++) a[r][j] -= f * a[c][j];
        }
    }
    for (int i = 0; i < 4; i++)
        for (int j = 0; j < 4; j++) out[i * 4 + j] = a[i][j + 4];
}

__device__ void make_proj(const float* p, float* o) {
    const float* ext = p;
    const float* K   = p + 16;
    for (int i = 0; i < 16; i++) o[i] = ext[i];
    for (int i = 0; i < 3; i++) {
        for (int j = 0; j < 4; j++) {
            float s = 0.f;
            for (int k = 0; k < 3; k++) s += K[i * 4 + k] * ext[k * 4 + j];
            o[i * 4 + j] = s;
        }
    }
}

// Per (b, src view): store rot(9) + trans(3) of src_proj @ inv(ref_proj)
__global__ void setup_proj_kernel(const float* __restrict__ proj,
                                  float* __restrict__ projp) {
    int t = threadIdx.x;
    if (t >= B_ * VS_) return;
    int b = t / VS_;
    int v = t % VS_ + 1;

    float refm[16], srcm[16], invr[16], P[16];
    make_proj(proj + ((size_t)(b * V_ + 0) * 2) * 16, refm);
    make_proj(proj + ((size_t)(b * V_ + v) * 2) * 16, srcm);
    inv4x4(refm, invr);
    for (int i = 0; i < 4; i++) {
        for (int j = 0; j < 4; j++) {
            float s = 0.f;
            for (int k = 0; k < 4; k++) s += srcm[i * 4 + k] * invr[k * 4 + j];
            P[i * 4 + j] = s;
        }
    }
    float* o = projp + t * 12;
    o[0] = P[0];  o[1] = P[1];  o[2]  = P[2];
    o[3] = P[4];  o[4] = P[5];  o[5]  = P[6];
    o[6] = P[8];  o[7] = P[9];  o[8]  = P[10];
    o[9] = P[3];  o[10] = P[7]; o[11] = P[11];
}

// ---------------------------------------------------------------------------
// (N, C, H, W) -> (N, H, W, C) fp32 channels-last transpose
// ---------------------------------------------------------------------------
__global__ __launch_bounds__(256) void transpose_kernel(const float* __restrict__ in,
                                                        float* __restrict__ out) {
    __shared__ float tile[C_][W_ + 1];
    int n = blockIdx.x / H_;
    int y = blockIdx.x % H_;
    for (int idx = threadIdx.x; idx < C_ * W_; idx += 256) {
        int c = idx / W_;
        int x = idx - c * W_;
        tile[c][x] = in[(((size_t)n * C_ + c) * H_ + y) * W_ + x];
    }
    __syncthreads();
    float* op = out + ((size_t)n * H_ + y) * W_ * C_;
    for (int idx = threadIdx.x; idx < W_ * C_; idx += 256) {
        int c = idx & (C_ - 1);
        int x = idx >> 5;
        op[idx] = tile[c][x];
    }
}

// ---------------------------------------------------------------------------
// Fused kernel with epipolar-cell dot-product dedup.
// Block = 8 pixels x 32 depths. Per (pixel, view): the 32 depth-lanes
// cooperatively compute ref·src dots over the bbox of integer tap cells
// (~15-55 cells), then each depth combines 4 dots bilinearly.
// ---------------------------------------------------------------------------
__global__ __launch_bounds__(256) void fused_kernel(const float* __restrict__ ref_fea,
                                                    const float* __restrict__ srcT,
                                                    const float* __restrict__ projp,
                                                    const float* __restrict__ depth_hypo,
                                                    const float* __restrict__ reg_w,
                                                    float* __restrict__ out) {
    const int WT = W_ / 8;
    int bid = blockIdx.x;
    int b   = bid / (H_ * WT);
    int rem = bid % (H_ * WT);
    int h   = rem / WT;
    int w0  = (rem % WT) * 8;

    int tid = threadIdx.x;
    int d   = tid & 31;
    int p   = tid >> 5;
    int w   = w0 + p;

    __shared__ float s_ref[8][36];
    __shared__ float s_rw[8][36];
    __shared__ float s_depth[8][33];
    __shared__ float s_dotS[8][CELLS_MAX];
    __shared__ float s_dotR[8][CELLS_MAX];
    {
        int c  = tid >> 3;
        int px = tid & 7;
        float val = ref_fea[(((size_t)b * C_ + c) * H_ + h) * W_ + w0 + px];
        s_ref[px][c] = val;
        s_rw[px][c]  = val * reg_w[c >> 2];
        s_depth[px][c] = depth_hypo[(((size_t)b * D_ + c) * H_ + h) * W_ + w0 + px];
    }
    __syncthreads();

    float depth = s_depth[p][d];
    float xf = (float)w, yf = (float)h;

    float Sv[VS_], Rv[VS_];
#pragma unroll
    for (int v = 0; v < VS_; ++v) {
        // ---- per-lane projective sample point ----
        const float* M = projp + (b * VS_ + v) * 12;
        float rx = M[0] * xf + M[1] * yf + M[2];
        float ry = M[3] * xf + M[4] * yf + M[5];
        float rz = M[6] * xf + M[7] * yf + M[8];
        float X = rx * depth + M[9];
        float Y = ry * depth + M[10];
        float Z = rz * depth + M[11];
        if (Z == 0.f) Z = 1e-9f;
        float ix = X / Z;
        float iy = Y / Z;
        float x0f = floorf(ix), y0f = floorf(iy);
        float wx1 = ix - x0f, wy1 = iy - y0f;
        float wx0 = 1.f - wx1, wy0 = 1.f - wy1;

        // int coords (clamped to avoid int overflow on wild projections)
        int x0 = (int)fminf(fmaxf(x0f, -2.f), (float)(W_ + 1));
        int y0 = (int)fminf(fmaxf(y0f, -2.f), (float)(H_ + 1));

        float vx0 = (x0f >= 0.f  && x0f <= (float)(W_ - 1)) ? 1.f : 0.f;
        float vx1 = (x0f >= -1.f && x0f <= (float)(W_ - 2)) ? 1.f : 0.f;
        float vy0 = (y0f >= 0.f  && y0f <= (float)(H_ - 1)) ? 1.f : 0.f;
        float vy1 = (y0f >= -1.f && y0f <= (float)(H_ - 2)) ? 1.f : 0.f;
        float ax0 = wx0 * vx0, ax1 = wx1 * vx1;
        float ay0 = wy0 * vy0, ay1 = wy1 * vy1;
        float w00 = ax0 * ay0, w10 = ax1 * ay0;
        float w01 = ax0 * ay1, w11 = ax1 * ay1;

        // ---- bbox of tap cells across the 32 depth lanes (per pixel) ----
        int xmn = x0, xmx = x0, ymn = y0, ymx = y0;
#pragma unroll
        for (int mask = 16; mask >= 1; mask >>= 1) {
            xmn = min(xmn, __shfl_xor(xmn, mask));
            xmx = max(xmx, __shfl_xor(xmx, mask));
            ymn = min(ymn, __shfl_xor(ymn, mask));
            ymx = max(ymx, __shfl_xor(ymx, mask));
        }
        xmn = max(xmn, -1); xmx = min(xmx, W_ - 1); if (xmx < xmn) xmx = xmn;
        ymn = max(ymn, -1); ymx = min(ymx, H_ - 1); if (ymx < ymn) ymx = ymn;
        int nx = xmx - xmn + 2;          // cells cover [xmn .. xmx+1]
        int ny = ymx - ymn + 2;
        int nc = nx * ny;
        bool coop = (nc <= CELLS_MAX);

        const float4* sp = (const float4*)(srcT + (size_t)(v * B_ + b) * H_ * W_ * C_);

        if (coop) {
            // ---- phase 1: cooperative dots over bbox cells ----
            for (int ci = d; ci < nc; ci += 32) {
                int cy = ci / nx;
                int cx = ci - cy * nx;
                int sx = min(max(xmn + cx, 0), W_ - 1);
                int sy = min(max(ymn + cy, 0), H_ - 1);
                const float4* cp = sp + ((size_t)sy * W_ + sx) * (C_ / 4);
                float dS = 0.f, dR = 0.f;
#pragma unroll
                for (int q = 0; q < 8; ++q) {
                    float4 sv = cp[q];
                    float4 r  = *(const float4*)&s_ref[p][q * 4];
                    float4 r2 = *(const float4*)&s_rw[p][q * 4];
                    dS += r.x  * sv.x + r.y  * sv.y + r.z  * sv.z + r.w  * sv.w;
                    dR += r2.x * sv.x + r2.y * sv.y + r2.z * sv.z + r2.w * sv.w;
                }
                s_dotS[p][ci] = dS;
                s_dotR[p][ci] = dR;
            }
        }
        __syncthreads();

        if (coop) {
            // ---- phase 2: bilinear combine of 4 cell dots ----
            int cx0 = min(max(x0 - xmn, 0), nx - 2);
            int cy0 = min(max(y0 - ymn, 0), ny - 2);
            int cb  = cy0 * nx + cx0;
            float d00 = s_dotS[p][cb],      d10 = s_dotS[p][cb + 1];
            float d01 = s_dotS[p][cb + nx], d11 = s_dotS[p][cb + nx + 1];
            Sv[v] = w00 * d00 + w10 * d10 + w01 * d01 + w11 * d11;
            float e00 = s_dotR[p][cb],      e10 = s_dotR[p][cb + 1];
            float e01 = s_dotR[p][cb + nx], e11 = s_dotR[p][cb + nx + 1];
            Rv[v] = w00 * e00 + w10 * e10 + w01 * e01 + w11 * e11;
        } else {
            // ---- fallback: direct per-depth gathers ----
            int xc0 = min(max(x0, 0), W_ - 1);
            int xc1 = min(max(x0 + 1, 0), W_ - 1);
            int yc0 = min(max(y0, 0), H_ - 1);
            int yc1 = min(max(y0 + 1, 0), H_ - 1);
            int o00 = (yc0 * W_ + xc0) * (C_ / 4);
            int o10 = (yc0 * W_ + xc1) * (C_ / 4);
            int o01 = (yc1 * W_ + xc0) * (C_ / 4);
            int o11 = (yc1 * W_ + xc1) * (C_ / 4);
            float sS = 0.f, sR = 0.f;
#pragma unroll
            for (int q = 0; q < 8; ++q) {
                float4 t00 = sp[o00 + q];
                float4 t10 = sp[o10 + q];
                float4 t01 = sp[o01 + q];
                float4 t11 = sp[o11 + q];
                float wsx = w00 * t00.x + w10 * t10.x + w01 * t01.x + w11 * t11.x;
                float wsy = w00 * t00.y + w10 * t10.y + w01 * t01.y + w11 * t11.y;
                float wsz = w00 * t00.z + w10 * t10.z + w01 * t01.z + w11 * t11.z;
                float wsw = w00 * t00.w + w10 * t10.w + w01 * t01.w + w11 * t11.w;
                float4 r  = *(const float4*)&s_ref[p][q * 4];
                float4 r2 = *(const float4*)&s_rw[p][q * 4];
                sS += r.x  * wsx + r.y  * wsy + r.z  * wsz + r.w  * wsw;
                sR += r2.x * wsx + r2.y * wsy + r2.z * wsz + r2.w * wsw;
            }
            Sv[v] = sS;
            Rv[v] = sR;
        }
        __syncthreads();   // dots buffer reused next view
    }

    // ---- per-view softmax over D + scalar accumulation ----
    float cwsum = 1e-8f;
    float acc   = 0.f;
#pragma unroll
    for (int v = 0; v < VS_; ++v) {
        float t = Sv[v] * 0.125f;  // *0.25 (group mean) * 0.5 (1/ATTN_TEMP)

        float m = t;
#pragma unroll
        for (int mask = 16; mask >= 1; mask >>= 1)
            m = fmaxf(m, __shfl_xor(m, mask));
        float e = __expf(t - m);
        float s = e;
#pragma unroll
        for (int mask = 16; mask >= 1; mask >>= 1)
            s += __shfl_xor(s, mask);
        float cw = e / s * 0.17677669529663689f;  // * 1/sqrt(C)

        cwsum += cw;
        acc   += cw * (Rv[v] * 0.25f);
    }

    float logit = acc / cwsum;

    // final softmax over D
    float m = logit;
#pragma unroll
    for (int mask = 16; mask >= 1; mask >>= 1)
        m = fmaxf(m, __shfl_xor(m, mask));
    float e = __expf(logit - m);
    float s = e;
#pragma unroll
    for (int mask = 16; mask >= 1; mask >>= 1)
        s += __shfl_xor(s, mask);
    float attn = e / s;

    // argmax over D (first max wins, matching jnp.argmax)
    float bv = logit;
    int   bi = d;
#pragma unroll
    for (int mask = 16; mask >= 1; mask >>= 1) {
        float ov = __shfl_xor(bv, mask);
        int   oi = __shfl_xor(bi, mask);
        if (ov > bv || (ov == bv && oi < bi)) { bv = ov; bi = oi; }
    }

    if (d == 0) {
        out[((size_t)b * H_ + h) * W_ + w] = s_depth[p][bi];
    }

    // attn store via LDS transpose for 32B-segment coalescing
    __shared__ float s_attn[8][33];
    s_attn[p][d] = attn;
    __syncthreads();
    int po = tid & 7;
    int d2 = tid >> 3;
    float* attn_out = out + (size_t)B_ * H_ * W_;
    attn_out[(((size_t)b * D_ + d2) * H_ + h) * W_ + w0 + po] = s_attn[po][d2];
}

// ---------------------------------------------------------------------------
extern "C" void kernel_launch(void* const* d_in, const int* in_sizes, int n_in,
                              void* d_out, int out_size, void* d_ws, size_t ws_size,
                              hipStream_t stream) {
    const float* ref_fea    = (const float*)d_in[0];
    const float* src_feas   = (const float*)d_in[1];
    const float* proj       = (const float*)d_in[2];
    const float* depth_hypo = (const float*)d_in[3];
    const float* reg_w      = (const float*)d_in[4];
    float* out = (float*)d_out;

    float* projp = (float*)d_ws;                       // 72 floats used
    float* srcT  = projp + 256;                        // VS*B*H*W*C fp32

    setup_proj_kernel<<<1, 64, 0, stream>>>(proj, projp);
    transpose_kernel<<<VS_ * B_ * H_, 256, 0, stream>>>(src_feas, srcT);
    fused_kernel<<<B_ * H_ * (W_ / 8), 256, 0, stream>>>(ref_fea, srcT, projp,
                                                         depth_hypo, reg_w, out);
}

// Round 8
// 98.474 us; speedup vs baseline: 4.0917x; 2.1056x over previous
//
#include <hip/hip_runtime.h>

#define B_  2
#define V_  4
#define VS_ 3   // source views
#define C_  32
#define G_  8
#define D_  32
#define H_  128
#define W_  160
#define CELLS_MAX 128   // nx<=16 (pitch) * ny<=8

// ---------------------------------------------------------------------------
// 4x4 inverse (Gauss-Jordan with partial pivoting)
// ---------------------------------------------------------------------------
__device__ void inv4x4(const float* m, float* out) {
    float a[4][8];
    for (int i = 0; i < 4; i++) {
        for (int j = 0; j < 4; j++) {
            a[i][j]     = m[i * 4 + j];
            a[i][j + 4] = (i == j) ? 1.f : 0.f;
        }
    }
    for (int c = 0; c < 4; c++) {
        int piv = c;
        float best = fabsf(a[c][c]);
        for (int r = c + 1; r < 4; r++) {
            float v = fabsf(a[r][c]);
            if (v > best) { best = v; piv = r; }
        }
        if (piv != c) {
            for (int j = 0; j < 8; j++) {
                float t = a[c][j]; a[c][j] = a[piv][j]; a[piv][j] = t;
            }
        }
        float pv = 1.f / a[c][c];
        for (int j = 0; j < 8; j++) a[c][j] *= pv;
        for (int r = 0; r < 4; r++) {
            if (r == c) continue;
            float f = a[r][c];
            for (int j = 0; j < 8; j++) a[r][j] -= f * a[c][j];
        }
    }
    for (int i = 0; i < 4; i++)
        for (int j = 0; j < 4; j++) out[i * 4 + j] = a[i][j + 4];
}

__device__ void make_proj(const float* p, float* o) {
    const float* ext = p;
    const float* K   = p + 16;
    for (int i = 0; i < 16; i++) o[i] = ext[i];
    for (int i = 0; i < 3; i++) {
        for (int j = 0; j < 4; j++) {
            float s = 0.f;
            for (int k = 0; k < 3; k++) s += K[i * 4 + k] * ext[k * 4 + j];
            o[i * 4 + j] = s;
        }
    }
}

// Per (b, src view): store rot(9) + trans(3) of src_proj @ inv(ref_proj)
__global__ void setup_proj_kernel(const float* __restrict__ proj,
                                  float* __restrict__ projp) {
    int t = threadIdx.x;
    if (t >= B_ * VS_) return;
    int b = t / VS_;
    int v = t % VS_ + 1;

    float refm[16], srcm[16], invr[16], P[16];
    make_proj(proj + ((size_t)(b * V_ + 0) * 2) * 16, refm);
    make_proj(proj + ((size_t)(b * V_ + v) * 2) * 16, srcm);
    inv4x4(refm, invr);
    for (int i = 0; i < 4; i++) {
        for (int j = 0; j < 4; j++) {
            float s = 0.f;
            for (int k = 0; k < 4; k++) s += srcm[i * 4 + k] * invr[k * 4 + j];
            P[i * 4 + j] = s;
        }
    }
    float* o = projp + t * 12;
    o[0] = P[0];  o[1] = P[1];  o[2]  = P[2];
    o[3] = P[4];  o[4] = P[5];  o[5]  = P[6];
    o[6] = P[8];  o[7] = P[9];  o[8]  = P[10];
    o[9] = P[3];  o[10] = P[7]; o[11] = P[11];
}

// ---------------------------------------------------------------------------
// (N, C, H, W) -> (N, H, W, C) fp32 channels-last transpose
// ---------------------------------------------------------------------------
__global__ __launch_bounds__(256) void transpose_kernel(const float* __restrict__ in,
                                                        float* __restrict__ out) {
    __shared__ float tile[C_][W_ + 1];
    int n = blockIdx.x / H_;
    int y = blockIdx.x % H_;
    for (int idx = threadIdx.x; idx < C_ * W_; idx += 256) {
        int c = idx / W_;
        int x = idx - c * W_;
        tile[c][x] = in[(((size_t)n * C_ + c) * H_ + y) * W_ + x];
    }
    __syncthreads();
    float* op = out + ((size_t)n * H_ + y) * W_ * C_;
    for (int idx = threadIdx.x; idx < W_ * C_; idx += 256) {
        int c = idx & (C_ - 1);
        int x = idx >> 5;
        op[idx] = tile[c][x];
    }
}

// ---------------------------------------------------------------------------
// Fused kernel, epipolar-cell dot dedup, lean version:
//  - per-pixel bbox computed analytically from the two depth endpoints
//    (projective map is monotone in d on [d0,d31]; no pole for this rig)
//  - single code path, never-binding safety caps keep LDS indexing in-bounds
//  - double-buffered dot LDS -> ONE barrier per view; next view's global
//    loads issue before current view's phase-2/softmax compute
// Block = 8 pixels x 32 depths.
// ---------------------------------------------------------------------------
__global__ __launch_bounds__(256) void fused_kernel(const float* __restrict__ ref_fea,
                                                    const float* __restrict__ srcT,
                                                    const float* __restrict__ projp,
                                                    const float* __restrict__ depth_hypo,
                                                    const float* __restrict__ reg_w,
                                                    float* __restrict__ out) {
    const int WT = W_ / 8;
    int bid = blockIdx.x;
    int b   = bid / (H_ * WT);
    int rem = bid % (H_ * WT);
    int h   = rem / WT;
    int w0  = (rem % WT) * 8;

    int tid = threadIdx.x;
    int d   = tid & 31;
    int p   = tid >> 5;
    int w   = w0 + p;

    __shared__ float  s_ref[8][36];
    __shared__ float  s_rw[8][36];
    __shared__ float  s_depth[8][33];
    __shared__ float2 s_dot[2][8][CELLS_MAX];   // 16 KB, double-buffered
    {
        int c  = tid >> 3;
        int px = tid & 7;
        float val = ref_fea[(((size_t)b * C_ + c) * H_ + h) * W_ + w0 + px];
        s_ref[px][c] = val;
        s_rw[px][c]  = val * reg_w[c >> 2];
        s_depth[px][c] = depth_hypo[(((size_t)b * D_ + c) * H_ + h) * W_ + w0 + px];
    }
    __syncthreads();

    float depth = s_depth[p][d];
    float d_lo  = s_depth[p][0];
    float d_hi  = s_depth[p][31];
    float xf = (float)w, yf = (float)h;

    // bbox state for current view (uniform across the 32 lanes of a pixel)
    int xmn, ymn, nx, ny, nxp, shp;

    // phase 1: compute per-cell dots for view v into s_dot[v&1]
    auto phase1 = [&](int v) {
        const float* M = projp + (b * VS_ + v) * 12;
        float rx = M[0] * xf + M[1] * yf + M[2];
        float ry = M[3] * xf + M[4] * yf + M[5];
        float rz = M[6] * xf + M[7] * yf + M[8];

        float Zl = rz * d_lo + M[11]; if (Zl == 0.f) Zl = 1e-9f;
        float Zh = rz * d_hi + M[11]; if (Zh == 0.f) Zh = 1e-9f;
        float il = 1.f / Zl, ih = 1.f / Zh;
        float xl = (rx * d_lo + M[9]) * il, yl = (ry * d_lo + M[10]) * il;
        float xh = (rx * d_hi + M[9]) * ih, yh = (ry * d_hi + M[10]) * ih;

        float xmnf = fminf(fmaxf(fminf(xl, xh), -2.f), (float)(W_ + 1));
        float xmxf = fminf(fmaxf(fmaxf(xl, xh), -2.f), (float)(W_ + 1));
        float ymnf = fminf(fmaxf(fminf(yl, yh), -2.f), (float)(H_ + 1));
        float ymxf = fminf(fmaxf(fmaxf(yl, yh), -2.f), (float)(H_ + 1));

        xmn = max((int)floorf(xmnf), -1);
        ymn = max((int)floorf(ymnf), -1);
        int xmx = min(max((int)floorf(xmxf), xmn), min(W_ - 1, xmn + 14));
        int ymx = min(max((int)floorf(ymxf), ymn), min(H_ - 1, ymn + 6));
        nx = xmx - xmn + 2;                 // cells cover [xmn .. xmx+1]
        ny = ymx - ymn + 2;
        shp = (nx <= 4) ? 2 : ((nx <= 8) ? 3 : 4);
        nxp = 1 << shp;
        int ncp = nxp * ny;                 // <= 128

        const float4* sp = (const float4*)(srcT + (size_t)(v * B_ + b) * H_ * W_ * C_);
        float2* dot = &s_dot[v & 1][p][0];
        for (int ci = d; ci < ncp; ci += 32) {
            int cx = ci & (nxp - 1);
            if (cx < nx) {
                int cy = ci >> shp;
                int sx = min(max(xmn + cx, 0), W_ - 1);
                int sy = min(max(ymn + cy, 0), H_ - 1);
                const float4* cp = sp + ((size_t)sy * W_ + sx) * (C_ / 4);
                float dS = 0.f, dR = 0.f;
#pragma unroll
                for (int q = 0; q < 8; ++q) {
                    float4 sv = cp[q];
                    float4 r  = *(const float4*)&s_ref[p][q * 4];
                    float4 r2 = *(const float4*)&s_rw[p][q * 4];
                    dS += r.x  * sv.x + r.y  * sv.y + r.z  * sv.z + r.w  * sv.w;
                    dR += r2.x * sv.x + r2.y * sv.y + r2.z * sv.z + r2.w * sv.w;
                }
                dot[ci] = make_float2(dS, dR);
            }
        }
    };

    float cwsum = 1e-8f;
    float acc   = 0.f;

    phase1(0);
    __syncthreads();

    for (int v = 0; v < VS_; ++v) {
        // save current view's bbox (phase1(v+1) overwrites the uniforms)
        int cxmn = xmn, cymn = ymn, cnx = nx, cny = ny, cnxp = nxp;

        if (v + 1 < VS_) phase1(v + 1);   // loads overlap phase-2 compute below

        // ---- phase 2: per-depth bilinear combine + view softmax ----
        const float* M = projp + (b * VS_ + v) * 12;
        float rx = M[0] * xf + M[1] * yf + M[2];
        float ry = M[3] * xf + M[4] * yf + M[5];
        float rz = M[6] * xf + M[7] * yf + M[8];
        float Z = rz * depth + M[11]; if (Z == 0.f) Z = 1e-9f;
        float iZ = 1.f / Z;
        float ix = (rx * depth + M[9]) * iZ;
        float iy = (ry * depth + M[10]) * iZ;
        float x0f = floorf(ix), y0f = floorf(iy);
        float wx1 = ix - x0f, wy1 = iy - y0f;
        float wx0 = 1.f - wx1, wy0 = 1.f - wy1;

        int x0 = (int)fminf(fmaxf(x0f, -2.f), (float)(W_ + 1));
        int y0 = (int)fminf(fmaxf(y0f, -2.f), (float)(H_ + 1));

        float vx0 = (x0f >= 0.f  && x0f <= (float)(W_ - 1)) ? 1.f : 0.f;
        float vx1 = (x0f >= -1.f && x0f <= (float)(W_ - 2)) ? 1.f : 0.f;
        float vy0 = (y0f >= 0.f  && y0f <= (float)(H_ - 1)) ? 1.f : 0.f;
        float vy1 = (y0f >= -1.f && y0f <= (float)(H_ - 2)) ? 1.f : 0.f;
        float ax0 = wx0 * vx0, ax1 = wx1 * vx1;
        float ay0 = wy0 * vy0, ay1 = wy1 * vy1;
        float w00 = ax0 * ay0, w10 = ax1 * ay0;
        float w01 = ax0 * ay1, w11 = ax1 * ay1;

        int cx0 = min(max(x0 - cxmn, 0), cnx - 2);
        int cy0 = min(max(y0 - cymn, 0), cny - 2);
        const float2* dot = &s_dot[v & 1][p][0];
        int cb = cy0 * cnxp + cx0;
        float2 d00 = dot[cb],        d10 = dot[cb + 1];
        float2 d01 = dot[cb + cnxp], d11 = dot[cb + cnxp + 1];
        float S = w00 * d00.x + w10 * d10.x + w01 * d01.x + w11 * d11.x;
        float R = w00 * d00.y + w10 * d10.y + w01 * d01.y + w11 * d11.y;

        // view softmax over D (32-lane butterfly)
        float t = S * 0.125f;   // *0.25 (group mean) * 0.5 (1/ATTN_TEMP)
        float m = t;
#pragma unroll
        for (int mask = 16; mask >= 1; mask >>= 1)
            m = fmaxf(m, __shfl_xor(m, mask));
        float e = __expf(t - m);
        float s = e;
#pragma unroll
        for (int mask = 16; mask >= 1; mask >>= 1)
            s += __shfl_xor(s, mask);
        float cw = e / s * 0.17677669529663689f;   // * 1/sqrt(C)
        cwsum += cw;
        acc   += cw * (R * 0.25f);

        __syncthreads();   // phase1(v+1) writes done; dot[v&1] free for v+2
    }

    float logit = acc / cwsum;

    // final softmax over D
    float m = logit;
#pragma unroll
    for (int mask = 16; mask >= 1; mask >>= 1)
        m = fmaxf(m, __shfl_xor(m, mask));
    float e = __expf(logit - m);
    float s = e;
#pragma unroll
    for (int mask = 16; mask >= 1; mask >>= 1)
        s += __shfl_xor(s, mask);
    float attn = e / s;

    // argmax over D (first max wins, matching jnp.argmax)
    float bv = logit;
    int   bi = d;
#pragma unroll
    for (int mask = 16; mask >= 1; mask >>= 1) {
        float ov = __shfl_xor(bv, mask);
        int   oi = __shfl_xor(bi, mask);
        if (ov > bv || (ov == bv && oi < bi)) { bv = ov; bi = oi; }
    }

    if (d == 0) {
        out[((size_t)b * H_ + h) * W_ + w] = s_depth[p][bi];
    }

    // attn store via LDS transpose for 32B-segment coalescing
    __shared__ float s_attn[8][33];
    s_attn[p][d] = attn;
    __syncthreads();
    int po = tid & 7;
    int d2 = tid >> 3;
    float* attn_out = out + (size_t)B_ * H_ * W_;
    attn_out[(((size_t)b * D_ + d2) * H_ + h) * W_ + w0 + po] = s_attn[po][d2];
}

// ---------------------------------------------------------------------------
extern "C" void kernel_launch(void* const* d_in, const int* in_sizes, int n_in,
                              void* d_out, int out_size, void* d_ws, size_t ws_size,
                              hipStream_t stream) {
    const float* ref_fea    = (const float*)d_in[0];
    const float* src_feas   = (const float*)d_in[1];
    const float* proj       = (const float*)d_in[2];
    const float* depth_hypo = (const float*)d_in[3];
    const float* reg_w      = (const float*)d_in[4];
    float* out = (float*)d_out;

    float* projp = (float*)d_ws;                       // 72 floats used
    float* srcT  = projp + 256;                        // VS*B*H*W*C fp32

    setup_proj_kernel<<<1, 64, 0, stream>>>(proj, projp);
    transpose_kernel<<<VS_ * B_ * H_, 256, 0, stream>>>(src_feas, srcT);
    fused_kernel<<<B_ * H_ * (W_ / 8), 256, 0, stream>>>(ref_fea, srcT, projp,
                                                         depth_hypo, reg_w, out);
}

// Round 9
// 98.324 us; speedup vs baseline: 4.0980x; 1.0015x over previous
//
#include <hip/hip_runtime.h>

#define B_  2
#define V_  4
#define VS_ 3   // source views
#define C_  32
#define G_  8
#define D_  32
#define H_  128
#define W_  160
#define CELLS_MAX 128   // nx<=16 (pitch) * ny<=8

// ---------------------------------------------------------------------------
// 4x4 inverse (Gauss-Jordan with partial pivoting)
// ---------------------------------------------------------------------------
__device__ void inv4x4(const float* m, float* out) {
    float a[4][8];
    for (int i = 0; i < 4; i++) {
        for (int j = 0; j < 4; j++) {
            a[i][j]     = m[i * 4 + j];
            a[i][j + 4] = (i == j) ? 1.f : 0.f;
        }
    }
    for (int c = 0; c < 4; c++) {
        int piv = c;
        float best = fabsf(a[c][c]);
        for (int r = c + 1; r < 4; r++) {
            float v = fabsf(a[r][c]);
            if (v > best) { best = v; piv = r; }
        }
        if (piv != c) {
            for (int j = 0; j < 8; j++) {
                float t = a[c][j]; a[c][j] = a[piv][j]; a[piv][j] = t;
            }
        }
        float pv = 1.f / a[c][c];
        for (int j = 0; j < 8; j++) a[c][j] *= pv;
        for (int r = 0; r < 4; r++) {
            if (r == c) continue;
            float f = a[r][c];
            for (int j = 0; j < 8; j++) a[r][j] -= f * a[c][j];
        }
    }
    for (int i = 0; i < 4; i++)
        for (int j = 0; j < 4; j++) out[i * 4 + j] = a[i][j + 4];
}

__device__ void make_proj(const float* p, float* o) {
    const float* ext = p;
    const float* K   = p + 16;
    for (int i = 0; i < 16; i++) o[i] = ext[i];
    for (int i = 0; i < 3; i++) {
        for (int j = 0; j < 4; j++) {
            float s = 0.f;
            for (int k = 0; k < 3; k++) s += K[i * 4 + k] * ext[k * 4 + j];
            o[i * 4 + j] = s;
        }
    }
}

// Per (b, src view): store rot(9) + trans(3) of src_proj @ inv(ref_proj)
__global__ void setup_proj_kernel(const float* __restrict__ proj,
                                  float* __restrict__ projp) {
    int t = threadIdx.x;
    if (t >= B_ * VS_) return;
    int b = t / VS_;
    int v = t % VS_ + 1;

    float refm[16], srcm[16], invr[16], P[16];
    make_proj(proj + ((size_t)(b * V_ + 0) * 2) * 16, refm);
    make_proj(proj + ((size_t)(b * V_ + v) * 2) * 16, srcm);
    inv4x4(refm, invr);
    for (int i = 0; i < 4; i++) {
        for (int j = 0; j < 4; j++) {
            float s = 0.f;
            for (int k = 0; k < 4; k++) s += srcm[i * 4 + k] * invr[k * 4 + j];
            P[i * 4 + j] = s;
        }
    }
    float* o = projp + t * 12;
    o[0] = P[0];  o[1] = P[1];  o[2]  = P[2];
    o[3] = P[4];  o[4] = P[5];  o[5]  = P[6];
    o[6] = P[8];  o[7] = P[9];  o[8]  = P[10];
    o[9] = P[3];  o[10] = P[7]; o[11] = P[11];
}

// ---------------------------------------------------------------------------
// (N, C, H, W) -> (N, H, W, C) fp32 channels-last transpose
// ---------------------------------------------------------------------------
__global__ __launch_bounds__(256) void transpose_kernel(const float* __restrict__ in,
                                                        float* __restrict__ out) {
    __shared__ float tile[C_][W_ + 1];
    int n = blockIdx.x / H_;
    int y = blockIdx.x % H_;
    for (int idx = threadIdx.x; idx < C_ * W_; idx += 256) {
        int c = idx / W_;
        int x = idx - c * W_;
        tile[c][x] = in[(((size_t)n * C_ + c) * H_ + y) * W_ + x];
    }
    __syncthreads();
    float* op = out + ((size_t)n * H_ + y) * W_ * C_;
    for (int idx = threadIdx.x; idx < W_ * C_; idx += 256) {
        int c = idx & (C_ - 1);
        int x = idx >> 5;
        op[idx] = tile[c][x];
    }
}

// ---------------------------------------------------------------------------
// Fused kernel, epipolar-cell dot dedup + group-dot factorization:
//  - per cell: 8 group dot4s; S = sum, R = sum(reg_w[g]*dot_g)  (47 ops, no s_rw)
//  - analytic per-pixel bbox from the two depth endpoints (monotone in d)
//  - double-buffered dot LDS, one barrier per view, next view's loads
//    overlap current view's phase-2/softmax
//  - __launch_bounds__(256,8): target the 64-VGPR occupancy cliff
// Block = 8 pixels x 32 depths.
// ---------------------------------------------------------------------------
__global__ __launch_bounds__(256, 8) void fused_kernel(const float* __restrict__ ref_fea,
                                                       const float* __restrict__ srcT,
                                                       const float* __restrict__ projp,
                                                       const float* __restrict__ depth_hypo,
                                                       const float* __restrict__ reg_w,
                                                       float* __restrict__ out) {
    const int WT = W_ / 8;
    int bid = blockIdx.x;
    int b   = bid / (H_ * WT);
    int rem = bid % (H_ * WT);
    int h   = rem / WT;
    int w0  = (rem % WT) * 8;

    int tid = threadIdx.x;
    int d   = tid & 31;
    int p   = tid >> 5;
    int w   = w0 + p;

    __shared__ float  s_ref[8][36];
    __shared__ float  s_depth[8][33];
    __shared__ float2 s_dot[2][8][CELLS_MAX];   // 16 KB, double-buffered
    {
        int c  = tid >> 3;
        int px = tid & 7;
        s_ref[px][c]   = ref_fea[(((size_t)b * C_ + c) * H_ + h) * W_ + w0 + px];
        s_depth[px][c] = depth_hypo[(((size_t)b * D_ + c) * H_ + h) * W_ + w0 + px];
    }

    // reg_w is wave-uniform -> scalar regs
    float rwv[G_];
#pragma unroll
    for (int g = 0; g < G_; ++g) rwv[g] = reg_w[g];

    __syncthreads();

    float depth = s_depth[p][d];
    float d_lo  = s_depth[p][0];
    float d_hi  = s_depth[p][31];
    float xf = (float)w, yf = (float)h;

    // bbox state for current view (uniform across the 32 lanes of a pixel)
    int xmn, ymn, nx, ny, nxp, shp;

    // phase 1: compute per-cell dots for view v into s_dot[v&1]
    auto phase1 = [&](int v) {
        const float* M = projp + (b * VS_ + v) * 12;
        float rx = M[0] * xf + M[1] * yf + M[2];
        float ry = M[3] * xf + M[4] * yf + M[5];
        float rz = M[6] * xf + M[7] * yf + M[8];

        float Zl = rz * d_lo + M[11]; if (Zl == 0.f) Zl = 1e-9f;
        float Zh = rz * d_hi + M[11]; if (Zh == 0.f) Zh = 1e-9f;
        float il = 1.f / Zl, ih = 1.f / Zh;
        float xl = (rx * d_lo + M[9]) * il, yl = (ry * d_lo + M[10]) * il;
        float xh = (rx * d_hi + M[9]) * ih, yh = (ry * d_hi + M[10]) * ih;

        float xmnf = fminf(fmaxf(fminf(xl, xh), -2.f), (float)(W_ + 1));
        float xmxf = fminf(fmaxf(fmaxf(xl, xh), -2.f), (float)(W_ + 1));
        float ymnf = fminf(fmaxf(fminf(yl, yh), -2.f), (float)(H_ + 1));
        float ymxf = fminf(fmaxf(fmaxf(yl, yh), -2.f), (float)(H_ + 1));

        xmn = max((int)floorf(xmnf), -1);
        ymn = max((int)floorf(ymnf), -1);
        int xmx = min(max((int)floorf(xmxf), xmn), min(W_ - 1, xmn + 14));
        int ymx = min(max((int)floorf(ymxf), ymn), min(H_ - 1, ymn + 6));
        nx = xmx - xmn + 2;                 // cells cover [xmn .. xmx+1]
        ny = ymx - ymn + 2;
        shp = (nx <= 4) ? 2 : ((nx <= 8) ? 3 : 4);
        nxp = 1 << shp;
        int ncp = nxp * ny;                 // <= 128

        const float4* sp = (const float4*)(srcT + (size_t)(v * B_ + b) * H_ * W_ * C_);
        float2* dot = &s_dot[v & 1][p][0];
        for (int ci = d; ci < ncp; ci += 32) {
            int cx = ci & (nxp - 1);
            if (cx < nx) {
                int cy = ci >> shp;
                int sx = min(max(xmn + cx, 0), W_ - 1);
                int sy = min(max(ymn + cy, 0), H_ - 1);
                const float4* cp = sp + ((size_t)sy * W_ + sx) * (C_ / 4);
                float dS = 0.f, dR = 0.f;
#pragma unroll
                for (int q = 0; q < 8; ++q) {
                    float4 sv = cp[q];
                    float4 r  = *(const float4*)&s_ref[p][q * 4];
                    float gq = r.x * sv.x + r.y * sv.y + r.z * sv.z + r.w * sv.w;
                    dS += gq;
                    dR += rwv[q] * gq;
                }
                dot[ci] = make_float2(dS, dR);
            }
        }
    };

    float cwsum = 1e-8f;
    float acc   = 0.f;

    phase1(0);
    __syncthreads();

    for (int v = 0; v < VS_; ++v) {
        // save current view's bbox (phase1(v+1) overwrites the uniforms)
        int cxmn = xmn, cymn = ymn, cnx = nx, cny = ny, cnxp = nxp;

        if (v + 1 < VS_) phase1(v + 1);   // loads overlap phase-2 compute below

        // ---- phase 2: per-depth bilinear combine + view softmax ----
        const float* M = projp + (b * VS_ + v) * 12;
        float rx = M[0] * xf + M[1] * yf + M[2];
        float ry = M[3] * xf + M[4] * yf + M[5];
        float rz = M[6] * xf + M[7] * yf + M[8];
        float Z = rz * depth + M[11]; if (Z == 0.f) Z = 1e-9f;
        float iZ = 1.f / Z;
        float ix = (rx * depth + M[9]) * iZ;
        float iy = (ry * depth + M[10]) * iZ;
        float x0f = floorf(ix), y0f = floorf(iy);
        float wx1 = ix - x0f, wy1 = iy - y0f;
        float wx0 = 1.f - wx1, wy0 = 1.f - wy1;

        int x0 = (int)fminf(fmaxf(x0f, -2.f), (float)(W_ + 1));
        int y0 = (int)fminf(fmaxf(y0f, -2.f), (float)(H_ + 1));

        float vx0 = (x0f >= 0.f  && x0f <= (float)(W_ - 1)) ? 1.f : 0.f;
        float vx1 = (x0f >= -1.f && x0f <= (float)(W_ - 2)) ? 1.f : 0.f;
        float vy0 = (y0f >= 0.f  && y0f <= (float)(H_ - 1)) ? 1.f : 0.f;
        float vy1 = (y0f >= -1.f && y0f <= (float)(H_ - 2)) ? 1.f : 0.f;
        float ax0 = wx0 * vx0, ax1 = wx1 * vx1;
        float ay0 = wy0 * vy0, ay1 = wy1 * vy1;
        float w00 = ax0 * ay0, w10 = ax1 * ay0;
        float w01 = ax0 * ay1, w11 = ax1 * ay1;

        int cx0 = min(max(x0 - cxmn, 0), cnx - 2);
        int cy0 = min(max(y0 - cymn, 0), cny - 2);
        const float2* dot = &s_dot[v & 1][p][0];
        int cb = cy0 * cnxp + cx0;
        float2 d00 = dot[cb],        d10 = dot[cb + 1];
        float2 d01 = dot[cb + cnxp], d11 = dot[cb + cnxp + 1];
        float S = w00 * d00.x + w10 * d10.x + w01 * d01.x + w11 * d11.x;
        float R = w00 * d00.y + w10 * d10.y + w01 * d01.y + w11 * d11.y;

        // view softmax over D (32-lane butterfly)
        float t = S * 0.125f;   // *0.25 (group mean) * 0.5 (1/ATTN_TEMP)
        float m = t;
#pragma unroll
        for (int mask = 16; mask >= 1; mask >>= 1)
            m = fmaxf(m, __shfl_xor(m, mask));
        float e = __expf(t - m);
        float s = e;
#pragma unroll
        for (int mask = 16; mask >= 1; mask >>= 1)
            s += __shfl_xor(s, mask);
        float cw = e / s * 0.17677669529663689f;   // * 1/sqrt(C)
        cwsum += cw;
        acc   += cw * (R * 0.25f);

        __syncthreads();   // phase1(v+1) writes done; dot[v&1] free for v+2
    }

    float logit = acc / cwsum;

    // final softmax over D
    float m = logit;
#pragma unroll
    for (int mask = 16; mask >= 1; mask >>= 1)
        m = fmaxf(m, __shfl_xor(m, mask));
    float e = __expf(logit - m);
    float s = e;
#pragma unroll
    for (int mask = 16; mask >= 1; mask >>= 1)
        s += __shfl_xor(s, mask);
    float attn = e / s;

    // argmax over D (first max wins, matching jnp.argmax)
    float bv = logit;
    int   bi = d;
#pragma unroll
    for (int mask = 16; mask >= 1; mask >>= 1) {
        float ov = __shfl_xor(bv, mask);
        int   oi = __shfl_xor(bi, mask);
        if (ov > bv || (ov == bv && oi < bi)) { bv = ov; bi = oi; }
    }

    if (d == 0) {
        out[((size_t)b * H_ + h) * W_ + w] = s_depth[p][bi];
    }

    // attn store via LDS transpose for 32B-segment coalescing
    __shared__ float s_attn[8][33];
    s_attn[p][d] = attn;
    __syncthreads();
    int po = tid & 7;
    int d2 = tid >> 3;
    float* attn_out = out + (size_t)B_ * H_ * W_;
    attn_out[(((size_t)b * D_ + d2) * H_ + h) * W_ + w0 + po] = s_attn[po][d2];
}

// ---------------------------------------------------------------------------
extern "C" void kernel_launch(void* const* d_in, const int* in_sizes, int n_in,
                              void* d_out, int out_size, void* d_ws, size_t ws_size,
                              hipStream_t stream) {
    const float* ref_fea    = (const float*)d_in[0];
    const float* src_feas   = (const float*)d_in[1];
    const float* proj       = (const float*)d_in[2];
    const float* depth_hypo = (const float*)d_in[3];
    const float* reg_w      = (const float*)d_in[4];
    float* out = (float*)d_out;

    float* projp = (float*)d_ws;                       // 72 floats used
    float* srcT  = projp + 256;                        // VS*B*H*W*C fp32

    setup_proj_kernel<<<1, 64, 0, stream>>>(proj, projp);
    transpose_kernel<<<VS_ * B_ * H_, 256, 0, stream>>>(src_feas, srcT);
    fused_kernel<<<B_ * H_ * (W_ / 8), 256, 0, stream>>>(ref_fea, srcT, projp,
                                                         depth_hypo, reg_w, out);
}